// Round 9
// baseline (351.047 us; speedup 1.0000x reference)
//
#include <hip/hip_runtime.h>

// FeatureSelfAttention: B=32, T=2048, F=64
// out[b,t,i]    = x[b,t,i] + gamma[i] * mixed[b,t,i]
// attn[b,t,i,j] = softmax_j( q_i * k_j / 8 ),  q = x Wq^T, k = x Wk^T.
//
// R9 = R2 EXACT structure and round-robin mapping, ONE change: the 16
// per-position X reads are hoisted into a prologue (per-wave LDS, single
// vmcnt drain) so the steady-state loop issues ONLY stores -- no vmcnt
// waits. Theory: vmcnt retires in order, so R2's per-position X load
// stalls until all previously-issued attn stores drain; under write
// backpressure that serializes compute with store drain each position
// (R6-B, with 6 loads/chunk interleaved, collapsed to 2.9 TB/s -- same
// mechanism, larger dose). Round-robin keeps the instantaneous write
// window dense (~64 MB); chunked scatter (R4/R8) is refuted.
//
// Pass 1: lane i owns row i (lane-local sum/mix, no reductions).
// Pass 2: coalesced attn write, 4 rows x 16 lanes, contiguous 1 KB float4
// wave-stores; exp2 recomputed with {qs, log2(inv)} broadcast from LDS.
// No max-subtraction: |qs*k| <= ~1.9 provably, softmax shift-invariant.

#define LOG2E 1.4426950408889634f

constexpr int F   = 64;
constexpr int PPW = 16;   // positions per wave

typedef _Float16 h2v __attribute__((ext_vector_type(2)));

#if defined(__has_builtin)
#if __has_builtin(__builtin_amdgcn_fdot2)
#define HAVE_FDOT2 1
#endif
#endif

static __device__ __forceinline__ float fdot2(h2v a, h2v b, float c) {
#ifdef HAVE_FDOT2
    return __builtin_amdgcn_fdot2(a, b, c, false);
#else
    return c + (float)a[0] * (float)b[0] + (float)a[1] * (float)b[1];
#endif
}

__global__ __launch_bounds__(256, 4)
void fsattn(const float* __restrict__ X,
            const float* __restrict__ Wq,
            const float* __restrict__ Wk,
            const float* __restrict__ gamma,
            float* __restrict__ out,
            float* __restrict__ attn,
            int BT)
{
    const int lane = threadIdx.x & 63;
    const int wid  = threadIdx.x >> 6;          // wave within block (0..3)
    const int gw   = (blockIdx.x << 2) + wid;   // global wave id
    const int nw   = gridDim.x << 2;

    // per-wave scratch; no cross-wave sharing -> wave_barriers only
    __shared__ float    xall [4][PPW][F];       // 16 positions of x
    __shared__ _Float16 xhall[4][PPW][F];       // f16 copy for dot2
    __shared__ float    k_lds[4][F];
    __shared__ float2   ql_lds[4][F];           // {qs, log2(inv)} per row

    // lane i holds row i of Wq/Wk as packed f16 pairs: 32+32 VGPRs
    h2v wq2[32], wk2[32];
#pragma unroll
    for (int p = 0; p < 32; ++p) {
        const float2 a = reinterpret_cast<const float2*>(Wq + lane * F)[p];
        const float2 b = reinterpret_cast<const float2*>(Wk + lane * F)[p];
        h2v ha; ha[0] = (_Float16)a.x; ha[1] = (_Float16)a.y;
        h2v hb; hb[0] = (_Float16)b.x; hb[1] = (_Float16)b.y;
        wq2[p] = ha; wk2[p] = hb;
    }
    const float g   = gamma[lane];
    const int   sub = lane >> 4;
    const int   c16 = lane & 15;

    // ---- prologue: ALL of this wave's global reads (16 round-robin rows),
    // drained before the first store is ever issued.
#pragma unroll
    for (int r = 0; r < PPW; ++r) {
        const int t = gw + r * nw;
        const float v = (t < BT) ? X[(size_t)t * F + lane] : 0.f;
        xall [wid][r][lane] = v;
        xhall[wid][r][lane] = (_Float16)v;
    }
    __builtin_amdgcn_wave_barrier();

    // ---- steady state: zero global loads -> zero vmcnt waits, pure stores
    for (int r = 0; r < PPW; ++r) {
        const int t = gw + r * nw;
        if (t >= BT) break;

        const float* xp  = &xall[wid][r][0];
        const h2v*   xhp = reinterpret_cast<const h2v*>(&xhall[wid][r][0]);
        const float  xv  = xp[lane];

        // q_i, k_i matvec: f16 dot2, x broadcast from LDS
        float q = 0.f, k = 0.f;
#pragma unroll
        for (int p = 0; p < 32; ++p) {
            const h2v xq = xhp[p];
            q = fdot2(wq2[p], xq, q);
            k = fdot2(wk2[p], xq, k);
        }
        const float qs = q * (0.125f * LOG2E);  // log2-domain scaled q
        k_lds[wid][lane] = k;
        __builtin_amdgcn_wave_barrier();

        // pass 1: per-lane row sum + mixed accumulation (no reductions)
        float sum0 = 0.f, sum1 = 0.f, mix0 = 0.f, mix1 = 0.f;
#pragma unroll
        for (int j = 0; j < 16; ++j) {
            const float4 k4 = reinterpret_cast<const float4*>(k_lds[wid])[j];
            const float4 x4 = reinterpret_cast<const float4*>(xp)[j];
            const float e0 = __builtin_amdgcn_exp2f(qs * k4.x);
            const float e1 = __builtin_amdgcn_exp2f(qs * k4.y);
            const float e2 = __builtin_amdgcn_exp2f(qs * k4.z);
            const float e3 = __builtin_amdgcn_exp2f(qs * k4.w);
            sum0 += e0 + e1;
            sum1 += e2 + e3;
            mix0 = __builtin_fmaf(e0, x4.x, __builtin_fmaf(e1, x4.y, mix0));
            mix1 = __builtin_fmaf(e2, x4.z, __builtin_fmaf(e3, x4.w, mix1));
        }
        const float sum = sum0 + sum1;
        const float inv = __builtin_amdgcn_rcpf(sum);
        const float li  = -__builtin_amdgcn_logf(sum);   // log2(1/sum)
        float2 ql; ql.x = qs; ql.y = li;
        ql_lds[wid][lane] = ql;
        __builtin_amdgcn_wave_barrier();

        out[(size_t)t * F + lane] = xv + g * ((mix0 + mix1) * inv);

        // pass 2: coalesced attn write. 64 lanes cover 4 rows x 16 float4
        // (one contiguous 1 KB segment per store). inv folded into exponent.
        float* ap = attn + (size_t)t * (F * F);
        const float4 kc = reinterpret_cast<const float4*>(k_lds[wid])[c16];
#pragma unroll
        for (int i0 = 0; i0 < F; i0 += 4) {
            const int row = i0 + sub;
            const float2 qr = ql_lds[wid][row];     // broadcast ds_read_b64
            float4 w;
            w.x = __builtin_amdgcn_exp2f(__builtin_fmaf(qr.x, kc.x, qr.y));
            w.y = __builtin_amdgcn_exp2f(__builtin_fmaf(qr.x, kc.y, qr.y));
            w.z = __builtin_amdgcn_exp2f(__builtin_fmaf(qr.x, kc.z, qr.y));
            w.w = __builtin_amdgcn_exp2f(__builtin_fmaf(qr.x, kc.w, qr.y));
            reinterpret_cast<float4*>(ap + (size_t)row * F)[c16] = w;
        }
        __builtin_amdgcn_wave_barrier();   // k_lds/ql_lds reused next position
    }
}

extern "C" void kernel_launch(void* const* d_in, const int* in_sizes, int n_in,
                              void* d_out, int out_size, void* d_ws, size_t ws_size,
                              hipStream_t stream) {
    const float* X     = (const float*)d_in[0];
    const float* Wq    = (const float*)d_in[1];
    const float* Wk    = (const float*)d_in[2];
    const float* gamma = (const float*)d_in[3];

    const int BT = in_sizes[0] / F;              // 65536 positions
    float* out  = (float*)d_out;                 // (B,T,F) first
    float* attn = out + (size_t)BT * F;          // then (B,T,F,F)

    // 1024 blocks x 4 waves = 4096 waves, 16 round-robin positions each
    hipLaunchKernelGGL(fsattn, dim3(1024), dim3(256), 0, stream,
                       X, Wq, Wk, gamma, out, attn, BT);
}

// Round 10
// 255.319 us; speedup vs baseline: 1.3749x; 1.3749x over previous
//
#include <hip/hip_runtime.h>

// FeatureSelfAttention: B=32, T=2048, F=64
// out[b,t,i]    = x[b,t,i] + gamma[i] * mixed[b,t,i]
// attn[b,t,i,j] = softmax_j( q_i * k_j / 8 ),  q = x Wq^T, k = x Wk^T.
//
// R10 = R2 byte-identical structure, ONE change: grid 1024 -> 512 blocks
// (2048 waves, 2 blocks/CU, 32 round-robin positions per wave).
// Theory: chip-wide OUTSTANDING-STORE population is what degrades the
// write path. Monotone evidence: fill ~890 waves -> 6.5 TB/s; R2 4096
// throttled waves (per-position X load bounds outstanding stores) ->
// 4.87; R8/R9 4096 unthrottled -> ~3.2; R6-B 8192 -> ~2.9. All other
// store-path theories (nt, address pattern, duty cycle, vmcnt order)
// tested and refuted. Halving streams tests dose-response; the
// per-position X load (natural throttle) is deliberately kept.
//
// Pass 1: lane i owns row i (lane-local sum/mix, no reductions).
// Pass 2: coalesced attn write, 4 rows x 16 lanes, contiguous 1 KB float4
// wave-stores; exp2 recomputed with {qs, log2(inv)} broadcast from LDS.
// No max-subtraction: |qs*k| <= ~1.9 provably, softmax shift-invariant.

#define LOG2E 1.4426950408889634f

constexpr int F = 64;

typedef _Float16 h2v __attribute__((ext_vector_type(2)));

#if defined(__has_builtin)
#if __has_builtin(__builtin_amdgcn_fdot2)
#define HAVE_FDOT2 1
#endif
#endif

static __device__ __forceinline__ float fdot2(h2v a, h2v b, float c) {
#ifdef HAVE_FDOT2
    return __builtin_amdgcn_fdot2(a, b, c, false);
#else
    return c + (float)a[0] * (float)b[0] + (float)a[1] * (float)b[1];
#endif
}

__global__ __launch_bounds__(256, 4)
void fsattn(const float* __restrict__ X,
            const float* __restrict__ Wq,
            const float* __restrict__ Wk,
            const float* __restrict__ gamma,
            float* __restrict__ out,
            float* __restrict__ attn,
            int BT)
{
    const int lane = threadIdx.x & 63;
    const int wid  = threadIdx.x >> 6;          // wave within block (0..3)
    const int gw   = (blockIdx.x << 2) + wid;   // global wave id
    const int nw   = gridDim.x << 2;

    // per-wave scratch; no cross-wave sharing -> only wave_barriers needed
    __shared__ float    x_lds[4][F];
    __shared__ float    k_lds[4][F];
    __shared__ _Float16 xh_lds[4][F];
    __shared__ float2   ql_lds[4][F];           // {qs, log2(inv)} per row

    // lane i holds row i of Wq/Wk as packed f16 pairs: 32+32 VGPRs
    h2v wq2[32], wk2[32];
#pragma unroll
    for (int p = 0; p < 32; ++p) {
        const float2 a = reinterpret_cast<const float2*>(Wq + lane * F)[p];
        const float2 b = reinterpret_cast<const float2*>(Wk + lane * F)[p];
        h2v ha; ha[0] = (_Float16)a.x; ha[1] = (_Float16)a.y;
        h2v hb; hb[0] = (_Float16)b.x; hb[1] = (_Float16)b.y;
        wq2[p] = ha; wk2[p] = hb;
    }
    const float g = gamma[lane];

    for (int t = gw; t < BT; t += nw) {
        const float xv = X[(size_t)t * F + lane];
        x_lds[wid][lane]  = xv;
        xh_lds[wid][lane] = (_Float16)xv;
        __builtin_amdgcn_wave_barrier();

        // q_i, k_i matvec: f16 dot2, x broadcast from LDS
        float q = 0.f, k = 0.f;
        const h2v* xh = reinterpret_cast<const h2v*>(xh_lds[wid]);
#pragma unroll
        for (int p = 0; p < 32; ++p) {
            const h2v xp = xh[p];
            q = fdot2(wq2[p], xp, q);
            k = fdot2(wk2[p], xp, k);
        }
        const float qs = q * (0.125f * LOG2E);  // log2-domain scaled q
        k_lds[wid][lane] = k;
        __builtin_amdgcn_wave_barrier();

        // pass 1: per-lane row sum + mixed accumulation (no reductions)
        float sum0 = 0.f, sum1 = 0.f, mix0 = 0.f, mix1 = 0.f;
#pragma unroll
        for (int j = 0; j < 16; ++j) {
            const float4 k4 = reinterpret_cast<const float4*>(k_lds[wid])[j];
            const float4 x4 = reinterpret_cast<const float4*>(x_lds[wid])[j];
            const float e0 = __builtin_amdgcn_exp2f(qs * k4.x);
            const float e1 = __builtin_amdgcn_exp2f(qs * k4.y);
            const float e2 = __builtin_amdgcn_exp2f(qs * k4.z);
            const float e3 = __builtin_amdgcn_exp2f(qs * k4.w);
            sum0 += e0 + e1;
            sum1 += e2 + e3;
            mix0 = __builtin_fmaf(e0, x4.x, __builtin_fmaf(e1, x4.y, mix0));
            mix1 = __builtin_fmaf(e2, x4.z, __builtin_fmaf(e3, x4.w, mix1));
        }
        const float sum = sum0 + sum1;
        const float inv = __builtin_amdgcn_rcpf(sum);
        const float li  = -__builtin_amdgcn_logf(sum);   // log2(inv)
        float2 ql; ql.x = qs; ql.y = li;
        ql_lds[wid][lane] = ql;
        __builtin_amdgcn_wave_barrier();

        out[(size_t)t * F + lane] = xv + g * ((mix0 + mix1) * inv);

        // pass 2: coalesced attn write. 64 lanes cover 4 rows x 16 float4
        // (one contiguous 1 KB segment per store). inv folded into exponent.
        float* ap = attn + (size_t)t * (F * F);
        const int sub = lane >> 4;
        const int c16 = lane & 15;
        const float4 kc = reinterpret_cast<const float4*>(k_lds[wid])[c16];
#pragma unroll
        for (int i0 = 0; i0 < F; i0 += 4) {
            const int row = i0 + sub;
            const float2 qr = ql_lds[wid][row];     // broadcast ds_read_b64
            float4 w;
            w.x = __builtin_amdgcn_exp2f(__builtin_fmaf(qr.x, kc.x, qr.y));
            w.y = __builtin_amdgcn_exp2f(__builtin_fmaf(qr.x, kc.y, qr.y));
            w.z = __builtin_amdgcn_exp2f(__builtin_fmaf(qr.x, kc.z, qr.y));
            w.w = __builtin_amdgcn_exp2f(__builtin_fmaf(qr.x, kc.w, qr.y));
            reinterpret_cast<float4*>(ap + (size_t)row * F)[c16] = w;
        }
    }
}

extern "C" void kernel_launch(void* const* d_in, const int* in_sizes, int n_in,
                              void* d_out, int out_size, void* d_ws, size_t ws_size,
                              hipStream_t stream) {
    const float* X     = (const float*)d_in[0];
    const float* Wq    = (const float*)d_in[1];
    const float* Wk    = (const float*)d_in[2];
    const float* gamma = (const float*)d_in[3];

    const int BT = in_sizes[0] / F;              // 65536 positions
    float* out  = (float*)d_out;                 // (B,T,F) first
    float* attn = out + (size_t)BT * F;          // then (B,T,F,F)

    // R10: 512 blocks (2048 waves, 2 blocks/CU) -- half of R2's stream count
    hipLaunchKernelGGL(fsattn, dim3(512), dim3(256), 0, stream,
                       X, Wq, Wk, gamma, out, attn, BT);
}